// Round 6
// baseline (4725.126 us; speedup 1.0000x reference)
//
#include <hip/hip_runtime.h>

#define N_NODES 100000
#define N_EDGES 1200000
#define LAYERS 4
#define SLOPE 0.01f

#define TILE 64
#define NTILES ((N_NODES + TILE - 1) / TILE)   // 1563

#define SCAN_ELEMS 1024
#define NB1 ((N_NODES + SCAN_ELEMS - 1) / SCAN_ELEMS)   // 98

__device__ __forceinline__ float leaky(float v) { return v >= 0.f ? v : SLOPE * v; }

// ---------------------------------------------------------------------------
// CSR build (counting sort by edge_dst) — unchanged
// ---------------------------------------------------------------------------
__global__ __launch_bounds__(256) void zero_counts(int* __restrict__ counts)
{
    int i = blockIdx.x * 256 + threadIdx.x;
    if (i < N_NODES) counts[i] = 0;
}

__global__ __launch_bounds__(256) void count_kernel(
    const int* __restrict__ dst, int* __restrict__ counts)
{
    int e = blockIdx.x * 256 + threadIdx.x;
    if (e < N_EDGES) atomicAdd(&counts[dst[e]], 1);
}

__global__ __launch_bounds__(256) void scan1_kernel(
    const int* __restrict__ counts, int* __restrict__ offs, int* __restrict__ bsum)
{
    __shared__ int s[256];
    int b = blockIdx.x, t = threadIdx.x;
    int base = b * SCAN_ELEMS;
    int v[4]; int sum = 0;
    #pragma unroll
    for (int u = 0; u < 4; u++) {
        int idx = base + t * 4 + u;
        int c = (idx < N_NODES) ? counts[idx] : 0;
        v[u] = sum; sum += c;
    }
    s[t] = sum; __syncthreads();
    for (int off = 1; off < 256; off <<= 1) {
        int y = (t >= off) ? s[t - off] : 0;
        __syncthreads();
        s[t] += y;
        __syncthreads();
    }
    int excl = s[t] - sum;
    #pragma unroll
    for (int u = 0; u < 4; u++) {
        int idx = base + t * 4 + u;
        if (idx < N_NODES) offs[idx] = excl + v[u];
    }
    if (t == 255) bsum[b] = s[255];
}

__global__ __launch_bounds__(128) void scan2_kernel(
    const int* __restrict__ bsum, int* __restrict__ bscan)
{
    __shared__ int s[128];
    int t = threadIdx.x;
    int c = (t < NB1) ? bsum[t] : 0;
    s[t] = c; __syncthreads();
    for (int off = 1; off < 128; off <<= 1) {
        int y = (t >= off) ? s[t - off] : 0;
        __syncthreads();
        s[t] += y;
        __syncthreads();
    }
    if (t < NB1) bscan[t] = s[t] - c;
}

__global__ __launch_bounds__(256) void scan3_kernel(
    int* __restrict__ offs, int* __restrict__ cursor, const int* __restrict__ bscan)
{
    int b = blockIdx.x, t = threadIdx.x;
    int base = b * SCAN_ELEMS;
    int add = bscan[b];
    #pragma unroll
    for (int u = 0; u < 4; u++) {
        int idx = base + t * 4 + u;
        if (idx < N_NODES) {
            int v = offs[idx] + add;
            offs[idx] = v;
            cursor[idx] = v;
        }
    }
    if (b == 0 && t == 0) offs[N_NODES] = N_EDGES;
}

__global__ __launch_bounds__(256) void fill_kernel(
    const int* __restrict__ src, const int* __restrict__ dst,
    const float* __restrict__ w, int* __restrict__ cursor,
    int2* __restrict__ ep)
{
    int e = blockIdx.x * 256 + threadIdx.x;
    if (e >= N_EDGES) return;
    int d = dst[e];
    int p = atomicAdd(&cursor[d], 1);
    ep[p] = make_int2(src[e], __float_as_int(w[e]));
}

// ---------------------------------------------------------------------------
// Dense kernels: weight-stationary tile GEMM.
// Block = 256 threads handles a TILE(=64)-node tile. Lane j owns output
// column j with that weight column preloaded in VGPRs (coalesced global
// load, once). Activations staged in LDS; per k-step all 64 lanes of a wave
// read the SAME LDS float4 (broadcast, conflict-free) — 1 ds_read_b128 per
// 16 lane-FMAs with 4-node ILP blocking. LN stats via 64-lane shfl_xor
// butterfly (lane j holds h[m][j]).
// ---------------------------------------------------------------------------

// Kernel A: encoder + LN(layer0) + dual GEMM(layer0)
__global__ __launch_bounds__(256, 3) void enc_ln_gemm(
    const float* __restrict__ x,
    const float* __restrict__ W1, const float* __restrict__ b1,
    const float* __restrict__ W2, const float* __restrict__ b2,
    const float* __restrict__ ln_g, const float* __restrict__ ln_b,
    const float* __restrict__ nodeW, const float* __restrict__ node_b,
    const float* __restrict__ edgeW, const float* __restrict__ edge_b,
    float* __restrict__ H, float* __restrict__ Y, float* __restrict__ Z)
{
    __shared__ float xs[TILE * 16];      // 4 KB
    __shared__ float hid_s[TILE * 128];  // 32 KB
    __shared__ float hn_s[TILE * 64];    // 16 KB

    const int tid = threadIdx.x;
    const int tile0 = blockIdx.x * TILE;
    const int nrem = N_NODES - tile0;

    // stage x tile: 64 nodes x 16 floats = 256 float4, one per thread
    {
        int node = tid >> 2, c = tid & 3;
        float4 v = make_float4(0.f, 0.f, 0.f, 0.f);
        if (node < nrem) v = ((const float4*)(x + (size_t)(tile0 + node) * 16))[c];
        ((float4*)xs)[tid] = v;
    }
    __syncthreads();

    // Phase 1: hid = leaky(x @ W1 + b1)   [TILE x 128]
    {
        int j = tid & 127, g = tid >> 7;            // 2 groups x 32 nodes
        float w[16];
        #pragma unroll
        for (int k = 0; k < 16; k++) w[k] = W1[k * 128 + j];
        float bj = b1[j];
        #pragma unroll
        for (int mm = 0; mm < 32; mm += 4) {
            int m = g * 32 + mm;
            const float4* r0 = (const float4*)(xs + (m + 0) * 16);
            const float4* r1 = (const float4*)(xs + (m + 1) * 16);
            const float4* r2 = (const float4*)(xs + (m + 2) * 16);
            const float4* r3 = (const float4*)(xs + (m + 3) * 16);
            float a0 = bj, a1 = bj, a2 = bj, a3 = bj;
            #pragma unroll
            for (int kk = 0; kk < 4; kk++) {
                float w0 = w[4*kk], w1 = w[4*kk+1], w2 = w[4*kk+2], w3 = w[4*kk+3];
                float4 v0 = r0[kk], v1 = r1[kk], v2 = r2[kk], v3 = r3[kk];
                a0 += v0.x*w0 + v0.y*w1 + v0.z*w2 + v0.w*w3;
                a1 += v1.x*w0 + v1.y*w1 + v1.z*w2 + v1.w*w3;
                a2 += v2.x*w0 + v2.y*w1 + v2.z*w2 + v2.w*w3;
                a3 += v3.x*w0 + v3.y*w1 + v3.z*w2 + v3.w*w3;
            }
            hid_s[(m + 0) * 128 + j] = leaky(a0);
            hid_s[(m + 1) * 128 + j] = leaky(a1);
            hid_s[(m + 2) * 128 + j] = leaky(a2);
            hid_s[(m + 3) * 128 + j] = leaky(a3);
        }
    }
    __syncthreads();

    // Phase 2: h = hid @ W2 + b2 ; LN -> hn  (two k-halves, w[] reused)
    {
        int j = tid & 63, g = tid >> 6;             // 4 groups x 16 nodes
        float gj = ln_g[j], bj = ln_b[j];
        float hv[16];
        float w[64];
        #pragma unroll
        for (int k = 0; k < 64; k++) w[k] = W2[k * 64 + j];
        float b2j = b2[j];
        #pragma unroll
        for (int mm = 0; mm < 16; mm += 4) {
            int m = g * 16 + mm;
            const float4* r0 = (const float4*)(hid_s + (m + 0) * 128);
            const float4* r1 = (const float4*)(hid_s + (m + 1) * 128);
            const float4* r2 = (const float4*)(hid_s + (m + 2) * 128);
            const float4* r3 = (const float4*)(hid_s + (m + 3) * 128);
            float a0 = b2j, a1 = b2j, a2 = b2j, a3 = b2j;
            #pragma unroll
            for (int kk = 0; kk < 16; kk++) {
                float w0 = w[4*kk], w1 = w[4*kk+1], w2 = w[4*kk+2], w3 = w[4*kk+3];
                float4 v0 = r0[kk], v1 = r1[kk], v2 = r2[kk], v3 = r3[kk];
                a0 += v0.x*w0 + v0.y*w1 + v0.z*w2 + v0.w*w3;
                a1 += v1.x*w0 + v1.y*w1 + v1.z*w2 + v1.w*w3;
                a2 += v2.x*w0 + v2.y*w1 + v2.z*w2 + v2.w*w3;
                a3 += v3.x*w0 + v3.y*w1 + v3.z*w2 + v3.w*w3;
            }
            hv[mm + 0] = a0; hv[mm + 1] = a1; hv[mm + 2] = a2; hv[mm + 3] = a3;
        }
        // second half of K
        #pragma unroll
        for (int k = 0; k < 64; k++) w[k] = W2[(k + 64) * 64 + j];
        #pragma unroll
        for (int mm = 0; mm < 16; mm += 4) {
            int m = g * 16 + mm;
            const float4* r0 = (const float4*)(hid_s + (m + 0) * 128 + 64);
            const float4* r1 = (const float4*)(hid_s + (m + 1) * 128 + 64);
            const float4* r2 = (const float4*)(hid_s + (m + 2) * 128 + 64);
            const float4* r3 = (const float4*)(hid_s + (m + 3) * 128 + 64);
            float a0 = hv[mm+0], a1 = hv[mm+1], a2 = hv[mm+2], a3 = hv[mm+3];
            #pragma unroll
            for (int kk = 0; kk < 16; kk++) {
                float w0 = w[4*kk], w1 = w[4*kk+1], w2 = w[4*kk+2], w3 = w[4*kk+3];
                float4 v0 = r0[kk], v1 = r1[kk], v2 = r2[kk], v3 = r3[kk];
                a0 += v0.x*w0 + v0.y*w1 + v0.z*w2 + v0.w*w3;
                a1 += v1.x*w0 + v1.y*w1 + v1.z*w2 + v1.w*w3;
                a2 += v2.x*w0 + v2.y*w1 + v2.z*w2 + v2.w*w3;
                a3 += v3.x*w0 + v3.y*w1 + v3.z*w2 + v3.w*w3;
            }
            hv[mm + 0] = a0; hv[mm + 1] = a1; hv[mm + 2] = a2; hv[mm + 3] = a3;
        }
        // LN per node (lane j holds col j; butterfly over the wave)
        #pragma unroll
        for (int mm = 0; mm < 16; mm++) {
            int m = g * 16 + mm;
            float hval = hv[mm];
            float s = hval, s2 = hval * hval;
            #pragma unroll
            for (int off = 1; off < 64; off <<= 1) {
                s  += __shfl_xor(s, off, 64);
                s2 += __shfl_xor(s2, off, 64);
            }
            float mu = s * (1.f / 64.f);
            float rs = rsqrtf(s2 * (1.f / 64.f) - mu * mu + 1e-5f);
            float hn = (hval - mu) * rs * gj + bj;
            hn_s[m * 64 + j] = hn;
            if (m < nrem) H[(size_t)(tile0 + m) * 64 + j] = hn;
        }
    }
    __syncthreads();

    // Phase 3: dual GEMM. lanes 0..31 -> Y cols, 32..63 -> Z cols
    {
        int j = tid & 63, g = tid >> 6;
        int jj = j & 31;
        const float* Wd = (j < 32) ? nodeW : edgeW;
        float bias = (j < 32) ? (node_b[jj] + edge_b[jj]) : 0.f;
        float* Od = (j < 32) ? Y : Z;
        float w[64];
        #pragma unroll
        for (int k = 0; k < 64; k++) w[k] = Wd[k * 32 + jj];
        #pragma unroll
        for (int mm = 0; mm < 16; mm += 4) {
            int m = g * 16 + mm;
            const float4* r0 = (const float4*)(hn_s + (m + 0) * 64);
            const float4* r1 = (const float4*)(hn_s + (m + 1) * 64);
            const float4* r2 = (const float4*)(hn_s + (m + 2) * 64);
            const float4* r3 = (const float4*)(hn_s + (m + 3) * 64);
            float a0 = bias, a1 = bias, a2 = bias, a3 = bias;
            #pragma unroll
            for (int kk = 0; kk < 16; kk++) {
                float w0 = w[4*kk], w1 = w[4*kk+1], w2 = w[4*kk+2], w3 = w[4*kk+3];
                float4 v0 = r0[kk], v1 = r1[kk], v2 = r2[kk], v3 = r3[kk];
                a0 += v0.x*w0 + v0.y*w1 + v0.z*w2 + v0.w*w3;
                a1 += v1.x*w0 + v1.y*w1 + v1.z*w2 + v1.w*w3;
                a2 += v2.x*w0 + v2.y*w1 + v2.z*w2 + v2.w*w3;
                a3 += v3.x*w0 + v3.y*w1 + v3.z*w2 + v3.w*w3;
            }
            if (m + 0 < nrem) Od[(size_t)(tile0 + m + 0) * 32 + jj] = a0;
            if (m + 1 < nrem) Od[(size_t)(tile0 + m + 1) * 32 + jj] = a1;
            if (m + 2 < nrem) Od[(size_t)(tile0 + m + 2) * 32 + jj] = a2;
            if (m + 3 < nrem) Od[(size_t)(tile0 + m + 3) * 32 + jj] = a3;
        }
    }
}

// ---------------------------------------------------------------------------
// Gather: Y[n] += sum over incoming edges of w_e * Z[src_e]  (8 lanes/node)
// ---------------------------------------------------------------------------
__global__ __launch_bounds__(256) void gather_kernel(
    const int* __restrict__ offs, const int2* __restrict__ ep,
    const float* __restrict__ Z, float* __restrict__ Y)
{
    int gid = blockIdx.x * 256 + threadIdx.x;
    int node = gid >> 3;
    int lane = gid & 7;
    if (node >= N_NODES) return;
    int p0 = offs[node], p1 = offs[node + 1];
    float4 acc = make_float4(0.f, 0.f, 0.f, 0.f);
    for (int p = p0; p < p1; p++) {
        int2 pr = ep[p];
        float we = __int_as_float(pr.y);
        float4 zv = ((const float4*)Z)[(size_t)pr.x * 8 + lane];
        acc.x += we * zv.x; acc.y += we * zv.y;
        acc.z += we * zv.z; acc.w += we * zv.w;
    }
    float4* yp = (float4*)(Y + (size_t)node * 32) + lane;
    float4 y = *yp;
    y.x += acc.x; y.y += acc.y; y.z += acc.z; y.w += acc.w;
    *yp = y;
}

// ---------------------------------------------------------------------------
// Kernel B: mlp+residual (layer l), LN + dual GEMM (layer l+1)
// ---------------------------------------------------------------------------
__global__ __launch_bounds__(256, 3) void mlp_ln_gemm(
    float* __restrict__ Yio, float* __restrict__ H, float* __restrict__ Z,
    const float* __restrict__ mlpW, const float* __restrict__ mlp_b,
    const float* __restrict__ ln_g, const float* __restrict__ ln_b,
    const float* __restrict__ nodeW, const float* __restrict__ node_b,
    const float* __restrict__ edgeW, const float* __restrict__ edge_b)
{
    __shared__ float lys[TILE * 32];     // 8 KB
    __shared__ float hn_s[TILE * 64];    // 16 KB

    const int tid = threadIdx.x;
    const int tile0 = blockIdx.x * TILE;
    const int nrem = N_NODES - tile0;

    // stage leaky(Y) tile: 64x32 = 512 float4, 2 per thread
    #pragma unroll
    for (int u = 0; u < 2; u++) {
        int idx = tid + u * 256;
        int node = idx >> 3, c = idx & 7;
        float4 v = make_float4(0.f, 0.f, 0.f, 0.f);
        if (node < nrem) v = ((const float4*)(Yio + (size_t)(tile0 + node) * 32))[c];
        v.x = leaky(v.x); v.y = leaky(v.y); v.z = leaky(v.z); v.w = leaky(v.w);
        ((float4*)lys)[idx] = v;
    }
    __syncthreads();

    // Phase 1: h = ly @ mlpW + mlp_b + H(residual) ; LN -> hn
    {
        int j = tid & 63, g = tid >> 6;             // 4 groups x 16 nodes
        float w[32];
        #pragma unroll
        for (int k = 0; k < 32; k++) w[k] = mlpW[k * 64 + j];
        float mbj = mlp_b[j], gj = ln_g[j], bj = ln_b[j];
        float hv[16];
        #pragma unroll
        for (int mm = 0; mm < 16; mm += 4) {
            int m = g * 16 + mm;
            const float4* r0 = (const float4*)(lys + (m + 0) * 32);
            const float4* r1 = (const float4*)(lys + (m + 1) * 32);
            const float4* r2 = (const float4*)(lys + (m + 2) * 32);
            const float4* r3 = (const float4*)(lys + (m + 3) * 32);
            float a0 = mbj, a1 = mbj, a2 = mbj, a3 = mbj;
            #pragma unroll
            for (int kk = 0; kk < 8; kk++) {
                float w0 = w[4*kk], w1 = w[4*kk+1], w2 = w[4*kk+2], w3 = w[4*kk+3];
                float4 v0 = r0[kk], v1 = r1[kk], v2 = r2[kk], v3 = r3[kk];
                a0 += v0.x*w0 + v0.y*w1 + v0.z*w2 + v0.w*w3;
                a1 += v1.x*w0 + v1.y*w1 + v1.z*w2 + v1.w*w3;
                a2 += v2.x*w0 + v2.y*w1 + v2.z*w2 + v2.w*w3;
                a3 += v3.x*w0 + v3.y*w1 + v3.z*w2 + v3.w*w3;
            }
            // residual (coalesced; 0 for pad nodes)
            a0 += (m + 0 < nrem) ? H[(size_t)(tile0 + m + 0) * 64 + j] : 0.f;
            a1 += (m + 1 < nrem) ? H[(size_t)(tile0 + m + 1) * 64 + j] : 0.f;
            a2 += (m + 2 < nrem) ? H[(size_t)(tile0 + m + 2) * 64 + j] : 0.f;
            a3 += (m + 3 < nrem) ? H[(size_t)(tile0 + m + 3) * 64 + j] : 0.f;
            hv[mm + 0] = a0; hv[mm + 1] = a1; hv[mm + 2] = a2; hv[mm + 3] = a3;
        }
        #pragma unroll
        for (int mm = 0; mm < 16; mm++) {
            int m = g * 16 + mm;
            float hval = hv[mm];
            float s = hval, s2 = hval * hval;
            #pragma unroll
            for (int off = 1; off < 64; off <<= 1) {
                s  += __shfl_xor(s, off, 64);
                s2 += __shfl_xor(s2, off, 64);
            }
            float mu = s * (1.f / 64.f);
            float rs = rsqrtf(s2 * (1.f / 64.f) - mu * mu + 1e-5f);
            float hn = (hval - mu) * rs * gj + bj;
            hn_s[m * 64 + j] = hn;
            if (m < nrem) H[(size_t)(tile0 + m) * 64 + j] = hn;
        }
    }
    __syncthreads();

    // Phase 2: dual GEMM -> Yio, Z
    {
        int j = tid & 63, g = tid >> 6;
        int jj = j & 31;
        const float* Wd = (j < 32) ? nodeW : edgeW;
        float bias = (j < 32) ? (node_b[jj] + edge_b[jj]) : 0.f;
        float* Od = (j < 32) ? Yio : Z;
        float w[64];
        #pragma unroll
        for (int k = 0; k < 64; k++) w[k] = Wd[k * 32 + jj];
        #pragma unroll
        for (int mm = 0; mm < 16; mm += 4) {
            int m = g * 16 + mm;
            const float4* r0 = (const float4*)(hn_s + (m + 0) * 64);
            const float4* r1 = (const float4*)(hn_s + (m + 1) * 64);
            const float4* r2 = (const float4*)(hn_s + (m + 2) * 64);
            const float4* r3 = (const float4*)(hn_s + (m + 3) * 64);
            float a0 = bias, a1 = bias, a2 = bias, a3 = bias;
            #pragma unroll
            for (int kk = 0; kk < 16; kk++) {
                float w0 = w[4*kk], w1 = w[4*kk+1], w2 = w[4*kk+2], w3 = w[4*kk+3];
                float4 v0 = r0[kk], v1 = r1[kk], v2 = r2[kk], v3 = r3[kk];
                a0 += v0.x*w0 + v0.y*w1 + v0.z*w2 + v0.w*w3;
                a1 += v1.x*w0 + v1.y*w1 + v1.z*w2 + v1.w*w3;
                a2 += v2.x*w0 + v2.y*w1 + v2.z*w2 + v2.w*w3;
                a3 += v3.x*w0 + v3.y*w1 + v3.z*w2 + v3.w*w3;
            }
            if (m + 0 < nrem) Od[(size_t)(tile0 + m + 0) * 32 + jj] = a0;
            if (m + 1 < nrem) Od[(size_t)(tile0 + m + 1) * 32 + jj] = a1;
            if (m + 2 < nrem) Od[(size_t)(tile0 + m + 2) * 32 + jj] = a2;
            if (m + 3 < nrem) Od[(size_t)(tile0 + m + 3) * 32 + jj] = a3;
        }
    }
}

// ---------------------------------------------------------------------------
// Kernel C: mlp+residual (layer 3) then decoder
// ---------------------------------------------------------------------------
__global__ __launch_bounds__(256, 3) void mlp_dec(
    const float* __restrict__ Y, const float* __restrict__ H,
    const float* __restrict__ mlpW, const float* __restrict__ mlp_b,
    const float* __restrict__ dW1, const float* __restrict__ db1,
    const float* __restrict__ dW2, const float* __restrict__ db2,
    float* __restrict__ out)
{
    __shared__ float lys[TILE * 32];      // 8 KB
    __shared__ float h_s[TILE * 64];      // 16 KB
    __shared__ float hid_s[TILE * 25];    // 6.25 KB (24 + pad)

    const int tid = threadIdx.x;
    const int tile0 = blockIdx.x * TILE;
    const int nrem = N_NODES - tile0;

    #pragma unroll
    for (int u = 0; u < 2; u++) {
        int idx = tid + u * 256;
        int node = idx >> 3, c = idx & 7;
        float4 v = make_float4(0.f, 0.f, 0.f, 0.f);
        if (node < nrem) v = ((const float4*)(Y + (size_t)(tile0 + node) * 32))[c];
        v.x = leaky(v.x); v.y = leaky(v.y); v.z = leaky(v.z); v.w = leaky(v.w);
        ((float4*)lys)[idx] = v;
    }
    __syncthreads();

    // Phase 1: h = ly @ mlpW + mlp_b + residual -> h_s (no LN)
    {
        int j = tid & 63, g = tid >> 6;
        float w[32];
        #pragma unroll
        for (int k = 0; k < 32; k++) w[k] = mlpW[k * 64 + j];
        float mbj = mlp_b[j];
        #pragma unroll
        for (int mm = 0; mm < 16; mm += 4) {
            int m = g * 16 + mm;
            const float4* r0 = (const float4*)(lys + (m + 0) * 32);
            const float4* r1 = (const float4*)(lys + (m + 1) * 32);
            const float4* r2 = (const float4*)(lys + (m + 2) * 32);
            const float4* r3 = (const float4*)(lys + (m + 3) * 32);
            float a0 = mbj, a1 = mbj, a2 = mbj, a3 = mbj;
            #pragma unroll
            for (int kk = 0; kk < 8; kk++) {
                float w0 = w[4*kk], w1 = w[4*kk+1], w2 = w[4*kk+2], w3 = w[4*kk+3];
                float4 v0 = r0[kk], v1 = r1[kk], v2 = r2[kk], v3 = r3[kk];
                a0 += v0.x*w0 + v0.y*w1 + v0.z*w2 + v0.w*w3;
                a1 += v1.x*w0 + v1.y*w1 + v1.z*w2 + v1.w*w3;
                a2 += v2.x*w0 + v2.y*w1 + v2.z*w2 + v2.w*w3;
                a3 += v3.x*w0 + v3.y*w1 + v3.z*w2 + v3.w*w3;
            }
            a0 += (m + 0 < nrem) ? H[(size_t)(tile0 + m + 0) * 64 + j] : 0.f;
            a1 += (m + 1 < nrem) ? H[(size_t)(tile0 + m + 1) * 64 + j] : 0.f;
            a2 += (m + 2 < nrem) ? H[(size_t)(tile0 + m + 2) * 64 + j] : 0.f;
            a3 += (m + 3 < nrem) ? H[(size_t)(tile0 + m + 3) * 64 + j] : 0.f;
            h_s[(m + 0) * 64 + j] = a0;
            h_s[(m + 1) * 64 + j] = a1;
            h_s[(m + 2) * 64 + j] = a2;
            h_s[(m + 3) * 64 + j] = a3;
        }
    }
    __syncthreads();

    // Phase 2: hid24 = leaky(h @ dW1 + db1)
    {
        int j = tid & 31, g = tid >> 5;             // 8 groups x 8 nodes
        if (j < 24) {
            float w[64];
            #pragma unroll
            for (int k = 0; k < 64; k++) w[k] = dW1[k * 24 + j];
            float bj = db1[j];
            #pragma unroll
            for (int mm = 0; mm < 8; mm += 4) {
                int m = g * 8 + mm;
                const float4* r0 = (const float4*)(h_s + (m + 0) * 64);
                const float4* r1 = (const float4*)(h_s + (m + 1) * 64);
                const float4* r2 = (const float4*)(h_s + (m + 2) * 64);
                const float4* r3 = (const float4*)(h_s + (m + 3) * 64);
                float a0 = bj, a1 = bj, a2 = bj, a3 = bj;
                #pragma unroll
                for (int kk = 0; kk < 16; kk++) {
                    float w0 = w[4*kk], w1 = w[4*kk+1], w2 = w[4*kk+2], w3 = w[4*kk+3];
                    float4 v0 = r0[kk], v1 = r1[kk], v2 = r2[kk], v3 = r3[kk];
                    a0 += v0.x*w0 + v0.y*w1 + v0.z*w2 + v0.w*w3;
                    a1 += v1.x*w0 + v1.y*w1 + v1.z*w2 + v1.w*w3;
                    a2 += v2.x*w0 + v2.y*w1 + v2.z*w2 + v2.w*w3;
                    a3 += v3.x*w0 + v3.y*w1 + v3.z*w2 + v3.w*w3;
                }
                hid_s[(m + 0) * 25 + j] = leaky(a0);
                hid_s[(m + 1) * 25 + j] = leaky(a1);
                hid_s[(m + 2) * 25 + j] = leaky(a2);
                hid_s[(m + 3) * 25 + j] = leaky(a3);
            }
        }
    }
    __syncthreads();

    // Phase 3: out3 = hid @ dW2 + db2  (one thread per node)
    if (tid < TILE && tid < nrem) {
        const float* hr = hid_s + tid * 25;
        float o0 = db2[0], o1 = db2[1], o2 = db2[2];
        #pragma unroll
        for (int t = 0; t < 24; t++) {
            float lt = hr[t];
            o0 += lt * dW2[t * 3 + 0];
            o1 += lt * dW2[t * 3 + 1];
            o2 += lt * dW2[t * 3 + 2];
        }
        float* op = out + (size_t)(tile0 + tid) * 3;
        op[0] = o0; op[1] = o1; op[2] = o2;
    }
}

// ---------------------------------------------------------------------------
extern "C" void kernel_launch(void* const* d_in, const int* in_sizes, int n_in,
                              void* d_out, int out_size, void* d_ws, size_t ws_size,
                              hipStream_t stream)
{
    const float* x      = (const float*)d_in[0];
    const int*   esrc   = (const int*)d_in[2];
    const int*   edst   = (const int*)d_in[3];
    const float* ew     = (const float*)d_in[4];
    const float* enc_W1 = (const float*)d_in[5];
    const float* enc_b1 = (const float*)d_in[6];
    const float* enc_W2 = (const float*)d_in[7];
    const float* enc_b2 = (const float*)d_in[8];
    const float* dec_W1 = (const float*)d_in[9];
    const float* dec_b1 = (const float*)d_in[10];
    const float* dec_W2 = (const float*)d_in[11];
    const float* dec_b2 = (const float*)d_in[12];
    const float* ln_g   = (const float*)d_in[13];
    const float* ln_b   = (const float*)d_in[14];
    const float* node_W = (const float*)d_in[15];
    const float* node_b = (const float*)d_in[16];
    const float* edge_W = (const float*)d_in[17];
    const float* edge_b = (const float*)d_in[18];
    const float* mlp_W  = (const float*)d_in[19];
    const float* mlp_b  = (const float*)d_in[20];

    // Workspace: floats H[N*64] | Y[N*32] | Z[N*32] | ep[E int2]
    //            ints counts[N] | offs[N+1] | cursor[N] | bsum | bscan
    float* H  = (float*)d_ws;
    float* Y  = H + (size_t)N_NODES * 64;
    float* Z  = Y + (size_t)N_NODES * 32;
    int2*  ep = (int2*)(Z + (size_t)N_NODES * 32);
    int* counts = (int*)(ep + N_EDGES);
    int* offs   = counts + N_NODES;
    int* cursor = offs + N_NODES + 1;
    int* bsum   = cursor + N_NODES;
    int* bscan  = bsum + NB1;

    const int nodeBlocks   = (N_NODES + 255) / 256;
    const int edgeBlocks   = (N_EDGES + 255) / 256;
    const int gatherBlocks = (N_NODES * 8 + 255) / 256;

    // --- CSR build (counting sort by dst) ---
    zero_counts<<<nodeBlocks, 256, 0, stream>>>(counts);
    count_kernel<<<edgeBlocks, 256, 0, stream>>>(edst, counts);
    scan1_kernel<<<NB1, 256, 0, stream>>>(counts, offs, bsum);
    scan2_kernel<<<1, 128, 0, stream>>>(bsum, bscan);
    scan3_kernel<<<NB1, 256, 0, stream>>>(offs, cursor, bscan);
    fill_kernel<<<edgeBlocks, 256, 0, stream>>>(esrc, edst, ew, cursor, ep);

    // --- network ---
    enc_ln_gemm<<<NTILES, 256, 0, stream>>>(
        x, enc_W1, enc_b1, enc_W2, enc_b2,
        ln_g, ln_b, node_W, node_b, edge_W, edge_b, H, Y, Z);

    for (int l = 0; l < LAYERS - 1; l++) {
        gather_kernel<<<gatherBlocks, 256, 0, stream>>>(offs, ep, Z, Y);
        mlp_ln_gemm<<<NTILES, 256, 0, stream>>>(
            Y, H, Z,
            mlp_W + l * 32 * 64, mlp_b + l * 64,
            ln_g + (l + 1) * 64, ln_b + (l + 1) * 64,
            node_W + (l + 1) * 64 * 32, node_b + (l + 1) * 32,
            edge_W + (l + 1) * 64 * 32, edge_b + (l + 1) * 32);
    }
    gather_kernel<<<gatherBlocks, 256, 0, stream>>>(offs, ep, Z, Y);
    mlp_dec<<<NTILES, 256, 0, stream>>>(
        Y, H, mlp_W + 3 * 32 * 64, mlp_b + 3 * 64,
        dec_W1, dec_b1, dec_W2, dec_b2, (float*)d_out);
}

// Round 8
// 1335.401 us; speedup vs baseline: 3.5384x; 3.5384x over previous
//
#include <hip/hip_runtime.h>

#define N_NODES 100000
#define N_EDGES 1200000
#define LAYERS 4
#define SLOPE 0.01f

#define SCAN_ELEMS 1024
#define NB1 ((N_NODES + SCAN_ELEMS - 1) / SCAN_ELEMS)   // 98

__device__ __forceinline__ float leaky(float v) { return v >= 0.f ? v : SLOPE * v; }

// float4 helper macros (all-static expansion -> named registers only).
// NOTE: macro params must NOT be named x/y/z/w (would capture member names).
#define DOT4(va,vb) ((va).x*(vb).x + (va).y*(vb).y + (va).z*(vb).z + (va).w*(vb).w)
#define SUM4(va)    ((va).x + (va).y + (va).z + (va).w)
#define FMA4(acc,sc,wv) { (acc).x += (sc)*(wv).x; (acc).y += (sc)*(wv).y; (acc).z += (sc)*(wv).z; (acc).w += (sc)*(wv).w; }
#define ADD4(va,vb) make_float4((va).x+(vb).x,(va).y+(vb).y,(va).z+(vb).z,(va).w+(vb).w)
#define LEAKY4(dv,sv) { (dv).x=leaky((sv).x); (dv).y=leaky((sv).y); (dv).z=leaky((sv).z); (dv).w=leaky((sv).w); }

// ---------------------------------------------------------------------------
// CSR build (counting sort by edge_dst) — unchanged, proven
// ---------------------------------------------------------------------------
__global__ __launch_bounds__(256) void zero_counts(int* __restrict__ counts)
{
    int i = blockIdx.x * 256 + threadIdx.x;
    if (i < N_NODES) counts[i] = 0;
}

__global__ __launch_bounds__(256) void count_kernel(
    const int* __restrict__ dst, int* __restrict__ counts)
{
    int e = blockIdx.x * 256 + threadIdx.x;
    if (e < N_EDGES) atomicAdd(&counts[dst[e]], 1);
}

__global__ __launch_bounds__(256) void scan1_kernel(
    const int* __restrict__ counts, int* __restrict__ offs, int* __restrict__ bsum)
{
    __shared__ int s[256];
    int b = blockIdx.x, t = threadIdx.x;
    int base = b * SCAN_ELEMS;
    int v[4]; int sum = 0;
    #pragma unroll
    for (int u = 0; u < 4; u++) {
        int idx = base + t * 4 + u;
        int c = (idx < N_NODES) ? counts[idx] : 0;
        v[u] = sum; sum += c;
    }
    s[t] = sum; __syncthreads();
    for (int off = 1; off < 256; off <<= 1) {
        int y = (t >= off) ? s[t - off] : 0;
        __syncthreads();
        s[t] += y;
        __syncthreads();
    }
    int excl = s[t] - sum;
    #pragma unroll
    for (int u = 0; u < 4; u++) {
        int idx = base + t * 4 + u;
        if (idx < N_NODES) offs[idx] = excl + v[u];
    }
    if (t == 255) bsum[b] = s[255];
}

__global__ __launch_bounds__(128) void scan2_kernel(
    const int* __restrict__ bsum, int* __restrict__ bscan)
{
    __shared__ int s[128];
    int t = threadIdx.x;
    int c = (t < NB1) ? bsum[t] : 0;
    s[t] = c; __syncthreads();
    for (int off = 1; off < 128; off <<= 1) {
        int y = (t >= off) ? s[t - off] : 0;
        __syncthreads();
        s[t] += y;
        __syncthreads();
    }
    if (t < NB1) bscan[t] = s[t] - c;
}

__global__ __launch_bounds__(256) void scan3_kernel(
    int* __restrict__ offs, int* __restrict__ cursor, const int* __restrict__ bscan)
{
    int b = blockIdx.x, t = threadIdx.x;
    int base = b * SCAN_ELEMS;
    int add = bscan[b];
    #pragma unroll
    for (int u = 0; u < 4; u++) {
        int idx = base + t * 4 + u;
        if (idx < N_NODES) {
            int v = offs[idx] + add;
            offs[idx] = v;
            cursor[idx] = v;
        }
    }
    if (b == 0 && t == 0) offs[N_NODES] = N_EDGES;
}

__global__ __launch_bounds__(256) void fill_kernel(
    const int* __restrict__ src, const int* __restrict__ dst,
    const float* __restrict__ w, int* __restrict__ cursor,
    int2* __restrict__ ep)
{
    int e = blockIdx.x * 256 + threadIdx.x;
    if (e >= N_EDGES) return;
    int d = dst[e];
    int p = atomicAdd(&cursor[d], 1);
    ep[p] = make_int2(src[e], __float_as_int(w[e]));
}

// transpose W1 [16][128] -> W1t [128][16]  (runs once, trivial)
__global__ __launch_bounds__(256) void transpose_W1(
    const float* __restrict__ W1, float* __restrict__ W1t)
{
    int idx = blockIdx.x * 256 + threadIdx.x;
    if (idx < 16 * 128) {
        int r = idx / 128, c = idx % 128;
        W1t[c * 16 + r] = W1[idx];
    }
}

// ---------------------------------------------------------------------------
// Dense kernels: ONE THREAD PER NODE, all state in NAMED float4 registers
// (no arrays -> nothing for PromoteAlloca to demote to scratch). Weight
// reads are wave-uniform -> scalar-cache path, overlapping the VALU.
// ---------------------------------------------------------------------------

// dual-GEMM macros: accumulate AY0..7 (Y cols) and AZ0..7 (Z cols) for one k
#define DUAL_K(sc,kk) { \
    const float4* nw_ = (const float4*)(nodeW + (size_t)(kk) * 32); \
    const float4* ew_ = (const float4*)(edgeW + (size_t)(kk) * 32); \
    float4 wv_; \
    wv_=nw_[0]; FMA4(AY0,(sc),wv_); wv_=nw_[1]; FMA4(AY1,(sc),wv_); \
    wv_=nw_[2]; FMA4(AY2,(sc),wv_); wv_=nw_[3]; FMA4(AY3,(sc),wv_); \
    wv_=nw_[4]; FMA4(AY4,(sc),wv_); wv_=nw_[5]; FMA4(AY5,(sc),wv_); \
    wv_=nw_[6]; FMA4(AY6,(sc),wv_); wv_=nw_[7]; FMA4(AY7,(sc),wv_); \
    wv_=ew_[0]; FMA4(AZ0,(sc),wv_); wv_=ew_[1]; FMA4(AZ1,(sc),wv_); \
    wv_=ew_[2]; FMA4(AZ2,(sc),wv_); wv_=ew_[3]; FMA4(AZ3,(sc),wv_); \
    wv_=ew_[4]; FMA4(AZ4,(sc),wv_); wv_=ew_[5]; FMA4(AZ5,(sc),wv_); \
    wv_=ew_[6]; FMA4(AZ6,(sc),wv_); wv_=ew_[7]; FMA4(AZ7,(sc),wv_); }

#define DUAL_H(Hv,kb) { float4 hh_=(Hv); \
    DUAL_K(hh_.x,(kb)+0) DUAL_K(hh_.y,(kb)+1) DUAL_K(hh_.z,(kb)+2) DUAL_K(hh_.w,(kb)+3) }

// mlp macros: accumulate H0..H15 for one k with activation sc
#define MLP_K(sc,kk) { \
    const float4* mw_ = (const float4*)(mlpW + (size_t)(kk) * 64); \
    float4 wv_; \
    wv_=mw_[0];  FMA4(H0,(sc),wv_);  wv_=mw_[1];  FMA4(H1,(sc),wv_); \
    wv_=mw_[2];  FMA4(H2,(sc),wv_);  wv_=mw_[3];  FMA4(H3,(sc),wv_); \
    wv_=mw_[4];  FMA4(H4,(sc),wv_);  wv_=mw_[5];  FMA4(H5,(sc),wv_); \
    wv_=mw_[6];  FMA4(H6,(sc),wv_);  wv_=mw_[7];  FMA4(H7,(sc),wv_); \
    wv_=mw_[8];  FMA4(H8,(sc),wv_);  wv_=mw_[9];  FMA4(H9,(sc),wv_); \
    wv_=mw_[10]; FMA4(H10,(sc),wv_); wv_=mw_[11]; FMA4(H11,(sc),wv_); \
    wv_=mw_[12]; FMA4(H12,(sc),wv_); wv_=mw_[13]; FMA4(H13,(sc),wv_); \
    wv_=mw_[14]; FMA4(H14,(sc),wv_); wv_=mw_[15]; FMA4(H15,(sc),wv_); }

#define MLP_LY(LYv,kb) { float4 ll_=(LYv); \
    MLP_K(ll_.x,(kb)+0) MLP_K(ll_.y,(kb)+1) MLP_K(ll_.z,(kb)+2) MLP_K(ll_.w,(kb)+3) }

// LN apply to one float4 (index i into g/b)
#define LN4(Hv,ii) { float4 g_=((const float4*)ln_g)[ii], b_=((const float4*)ln_b)[ii]; \
    (Hv).x=((Hv).x-mu)*rs*g_.x+b_.x; (Hv).y=((Hv).y-mu)*rs*g_.y+b_.y; \
    (Hv).z=((Hv).z-mu)*rs*g_.z+b_.z; (Hv).w=((Hv).w-mu)*rs*g_.w+b_.w; }

// decoder macros
#define DEC_K(sc,kk) { \
    const float4* dw_ = (const float4*)(dW1 + (size_t)(kk) * 24); \
    float4 wv_; \
    wv_=dw_[0]; FMA4(D0,(sc),wv_); wv_=dw_[1]; FMA4(D1,(sc),wv_); \
    wv_=dw_[2]; FMA4(D2,(sc),wv_); wv_=dw_[3]; FMA4(D3,(sc),wv_); \
    wv_=dw_[4]; FMA4(D4,(sc),wv_); wv_=dw_[5]; FMA4(D5,(sc),wv_); }

#define DEC_H(Hv,kb) { float4 hh_=(Hv); \
    DEC_K(hh_.x,(kb)+0) DEC_K(hh_.y,(kb)+1) DEC_K(hh_.z,(kb)+2) DEC_K(hh_.w,(kb)+3) }

#define OUT_T(lv,tt) { float lt_=leaky(lv); \
    o0 += lt_*dW2[(tt)*3+0]; o1 += lt_*dW2[(tt)*3+1]; o2 += lt_*dW2[(tt)*3+2]; }

#define OUT_D(Dv,tb) { float4 dd_=(Dv); \
    OUT_T(dd_.x,(tb)+0) OUT_T(dd_.y,(tb)+1) OUT_T(dd_.z,(tb)+2) OUT_T(dd_.w,(tb)+3) }

// Kernel A: encoder + LN(layer0) + dual GEMM(layer0)
__global__ __launch_bounds__(256, 1) void enc_ln_gemm(
    const float* __restrict__ x,
    const float* __restrict__ W1t, const float* __restrict__ b1,
    const float* __restrict__ W2, const float* __restrict__ b2,
    const float* __restrict__ ln_g, const float* __restrict__ ln_b,
    const float* __restrict__ nodeW, const float* __restrict__ node_b,
    const float* __restrict__ edgeW, const float* __restrict__ edge_b,
    float* __restrict__ H, float* __restrict__ Y, float* __restrict__ Z)
{
    int gid = blockIdx.x * 256 + threadIdx.x;
    bool on = gid < N_NODES;
    int n = on ? gid : N_NODES - 1;

    const float4* xv = (const float4*)(x + (size_t)n * 16);
    float4 X0 = xv[0], X1 = xv[1], X2 = xv[2], X3 = xv[3];

    const float4* B2 = (const float4*)b2;
    float4 H0=B2[0], H1=B2[1], H2=B2[2], H3=B2[3], H4=B2[4], H5=B2[5], H6=B2[6], H7=B2[7];
    float4 H8=B2[8], H9=B2[9], H10=B2[10], H11=B2[11], H12=B2[12], H13=B2[13], H14=B2[14], H15=B2[15];

    for (int k = 0; k < 128; k++) {
        const float4* wc = (const float4*)(W1t + k * 16);
        float t = b1[k] + DOT4(X0, wc[0]) + DOT4(X1, wc[1]) + DOT4(X2, wc[2]) + DOT4(X3, wc[3]);
        t = leaky(t);
        const float4* wr = (const float4*)(W2 + (size_t)k * 64);
        float4 wv_;
        wv_=wr[0];  FMA4(H0,t,wv_);  wv_=wr[1];  FMA4(H1,t,wv_);
        wv_=wr[2];  FMA4(H2,t,wv_);  wv_=wr[3];  FMA4(H3,t,wv_);
        wv_=wr[4];  FMA4(H4,t,wv_);  wv_=wr[5];  FMA4(H5,t,wv_);
        wv_=wr[6];  FMA4(H6,t,wv_);  wv_=wr[7];  FMA4(H7,t,wv_);
        wv_=wr[8];  FMA4(H8,t,wv_);  wv_=wr[9];  FMA4(H9,t,wv_);
        wv_=wr[10]; FMA4(H10,t,wv_); wv_=wr[11]; FMA4(H11,t,wv_);
        wv_=wr[12]; FMA4(H12,t,wv_); wv_=wr[13]; FMA4(H13,t,wv_);
        wv_=wr[14]; FMA4(H14,t,wv_); wv_=wr[15]; FMA4(H15,t,wv_);
    }

    // LayerNorm
    float s = SUM4(H0)+SUM4(H1)+SUM4(H2)+SUM4(H3)+SUM4(H4)+SUM4(H5)+SUM4(H6)+SUM4(H7)
            + SUM4(H8)+SUM4(H9)+SUM4(H10)+SUM4(H11)+SUM4(H12)+SUM4(H13)+SUM4(H14)+SUM4(H15);
    float s2 = DOT4(H0,H0)+DOT4(H1,H1)+DOT4(H2,H2)+DOT4(H3,H3)+DOT4(H4,H4)+DOT4(H5,H5)+DOT4(H6,H6)+DOT4(H7,H7)
             + DOT4(H8,H8)+DOT4(H9,H9)+DOT4(H10,H10)+DOT4(H11,H11)+DOT4(H12,H12)+DOT4(H13,H13)+DOT4(H14,H14)+DOT4(H15,H15);
    float mu = s * (1.f / 64.f);
    float rs = rsqrtf(s2 * (1.f / 64.f) - mu * mu + 1e-5f);
    LN4(H0,0) LN4(H1,1) LN4(H2,2) LN4(H3,3) LN4(H4,4) LN4(H5,5) LN4(H6,6) LN4(H7,7)
    LN4(H8,8) LN4(H9,9) LN4(H10,10) LN4(H11,11) LN4(H12,12) LN4(H13,13) LN4(H14,14) LN4(H15,15)

    if (on) {
        float4* hp = (float4*)(H + (size_t)n * 64);
        hp[0]=H0; hp[1]=H1; hp[2]=H2; hp[3]=H3; hp[4]=H4; hp[5]=H5; hp[6]=H6; hp[7]=H7;
        hp[8]=H8; hp[9]=H9; hp[10]=H10; hp[11]=H11; hp[12]=H12; hp[13]=H13; hp[14]=H14; hp[15]=H15;
    }

    // dual GEMM
    const float4* NBp = (const float4*)node_b;
    const float4* EBp = (const float4*)edge_b;
    float4 AY0=ADD4(NBp[0],EBp[0]), AY1=ADD4(NBp[1],EBp[1]), AY2=ADD4(NBp[2],EBp[2]), AY3=ADD4(NBp[3],EBp[3]);
    float4 AY4=ADD4(NBp[4],EBp[4]), AY5=ADD4(NBp[5],EBp[5]), AY6=ADD4(NBp[6],EBp[6]), AY7=ADD4(NBp[7],EBp[7]);
    float4 AZ0=make_float4(0,0,0,0), AZ1=AZ0, AZ2=AZ0, AZ3=AZ0, AZ4=AZ0, AZ5=AZ0, AZ6=AZ0, AZ7=AZ0;

    DUAL_H(H0,0)  DUAL_H(H1,4)  DUAL_H(H2,8)   DUAL_H(H3,12)
    DUAL_H(H4,16) DUAL_H(H5,20) DUAL_H(H6,24)  DUAL_H(H7,28)
    DUAL_H(H8,32) DUAL_H(H9,36) DUAL_H(H10,40) DUAL_H(H11,44)
    DUAL_H(H12,48) DUAL_H(H13,52) DUAL_H(H14,56) DUAL_H(H15,60)

    if (on) {
        float4* yp = (float4*)(Y + (size_t)n * 32);
        float4* zp = (float4*)(Z + (size_t)n * 32);
        yp[0]=AY0; yp[1]=AY1; yp[2]=AY2; yp[3]=AY3; yp[4]=AY4; yp[5]=AY5; yp[6]=AY6; yp[7]=AY7;
        zp[0]=AZ0; zp[1]=AZ1; zp[2]=AZ2; zp[3]=AZ3; zp[4]=AZ4; zp[5]=AZ5; zp[6]=AZ6; zp[7]=AZ7;
    }
}

// ---------------------------------------------------------------------------
// Gather: Y[n] += sum over incoming edges of w_e * Z[src_e]  (8 lanes/node)
// ---------------------------------------------------------------------------
__global__ __launch_bounds__(256) void gather_kernel(
    const int* __restrict__ offs, const int2* __restrict__ ep,
    const float* __restrict__ Z, float* __restrict__ Y)
{
    int gid = blockIdx.x * 256 + threadIdx.x;
    int node = gid >> 3;
    int lane = gid & 7;
    if (node >= N_NODES) return;
    int p0 = offs[node], p1 = offs[node + 1];
    float4 acc = make_float4(0.f, 0.f, 0.f, 0.f);
    for (int p = p0; p < p1; p++) {
        int2 pr = ep[p];
        float we = __int_as_float(pr.y);
        float4 zv = ((const float4*)Z)[(size_t)pr.x * 8 + lane];
        acc.x += we * zv.x; acc.y += we * zv.y;
        acc.z += we * zv.z; acc.w += we * zv.w;
    }
    float4* yp = (float4*)(Y + (size_t)node * 32) + lane;
    float4 y = *yp;
    y.x += acc.x; y.y += acc.y; y.z += acc.z; y.w += acc.w;
    *yp = y;
}

// ---------------------------------------------------------------------------
// Kernel B: mlp+residual (layer l) then LN + dual GEMM (layer l+1)
// ---------------------------------------------------------------------------
__global__ __launch_bounds__(256, 1) void mlp_ln_gemm(
    float* __restrict__ Yio, float* __restrict__ H, float* __restrict__ Z,
    const float* __restrict__ mlpW, const float* __restrict__ mlp_b,
    const float* __restrict__ ln_g, const float* __restrict__ ln_b,
    const float* __restrict__ nodeW, const float* __restrict__ node_b,
    const float* __restrict__ edgeW, const float* __restrict__ edge_b)
{
    int gid = blockIdx.x * 256 + threadIdx.x;
    bool on = gid < N_NODES;
    int n = on ? gid : N_NODES - 1;

    const float4* yv = (const float4*)(Yio + (size_t)n * 32);
    float4 LY0,LY1,LY2,LY3,LY4,LY5,LY6,LY7;
    { float4 t;
      t=yv[0]; LEAKY4(LY0,t) t=yv[1]; LEAKY4(LY1,t)
      t=yv[2]; LEAKY4(LY2,t) t=yv[3]; LEAKY4(LY3,t)
      t=yv[4]; LEAKY4(LY4,t) t=yv[5]; LEAKY4(LY5,t)
      t=yv[6]; LEAKY4(LY6,t) t=yv[7]; LEAKY4(LY7,t) }

    const float4* MBp = (const float4*)mlp_b;
    float4 H0=MBp[0], H1=MBp[1], H2=MBp[2], H3=MBp[3], H4=MBp[4], H5=MBp[5], H6=MBp[6], H7=MBp[7];
    float4 H8=MBp[8], H9=MBp[9], H10=MBp[10], H11=MBp[11], H12=MBp[12], H13=MBp[13], H14=MBp[14], H15=MBp[15];

    MLP_LY(LY0,0)  MLP_LY(LY1,4)  MLP_LY(LY2,8)  MLP_LY(LY3,12)
    MLP_LY(LY4,16) MLP_LY(LY5,20) MLP_LY(LY6,24) MLP_LY(LY7,28)

    // residual
    float4* hp = (float4*)(H + (size_t)n * 64);
    { float4 r;
      r=hp[0]; H0=ADD4(H0,r);   r=hp[1]; H1=ADD4(H1,r);
      r=hp[2]; H2=ADD4(H2,r);   r=hp[3]; H3=ADD4(H3,r);
      r=hp[4]; H4=ADD4(H4,r);   r=hp[5]; H5=ADD4(H5,r);
      r=hp[6]; H6=ADD4(H6,r);   r=hp[7]; H7=ADD4(H7,r);
      r=hp[8]; H8=ADD4(H8,r);   r=hp[9]; H9=ADD4(H9,r);
      r=hp[10]; H10=ADD4(H10,r); r=hp[11]; H11=ADD4(H11,r);
      r=hp[12]; H12=ADD4(H12,r); r=hp[13]; H13=ADD4(H13,r);
      r=hp[14]; H14=ADD4(H14,r); r=hp[15]; H15=ADD4(H15,r); }

    // LN
    float s = SUM4(H0)+SUM4(H1)+SUM4(H2)+SUM4(H3)+SUM4(H4)+SUM4(H5)+SUM4(H6)+SUM4(H7)
            + SUM4(H8)+SUM4(H9)+SUM4(H10)+SUM4(H11)+SUM4(H12)+SUM4(H13)+SUM4(H14)+SUM4(H15);
    float s2 = DOT4(H0,H0)+DOT4(H1,H1)+DOT4(H2,H2)+DOT4(H3,H3)+DOT4(H4,H4)+DOT4(H5,H5)+DOT4(H6,H6)+DOT4(H7,H7)
             + DOT4(H8,H8)+DOT4(H9,H9)+DOT4(H10,H10)+DOT4(H11,H11)+DOT4(H12,H12)+DOT4(H13,H13)+DOT4(H14,H14)+DOT4(H15,H15);
    float mu = s * (1.f / 64.f);
    float rs = rsqrtf(s2 * (1.f / 64.f) - mu * mu + 1e-5f);
    LN4(H0,0) LN4(H1,1) LN4(H2,2) LN4(H3,3) LN4(H4,4) LN4(H5,5) LN4(H6,6) LN4(H7,7)
    LN4(H8,8) LN4(H9,9) LN4(H10,10) LN4(H11,11) LN4(H12,12) LN4(H13,13) LN4(H14,14) LN4(H15,15)

    if (on) {
        hp[0]=H0; hp[1]=H1; hp[2]=H2; hp[3]=H3; hp[4]=H4; hp[5]=H5; hp[6]=H6; hp[7]=H7;
        hp[8]=H8; hp[9]=H9; hp[10]=H10; hp[11]=H11; hp[12]=H12; hp[13]=H13; hp[14]=H14; hp[15]=H15;
    }

    // dual GEMM
    const float4* NBp = (const float4*)node_b;
    const float4* EBp = (const float4*)edge_b;
    float4 AY0=ADD4(NBp[0],EBp[0]), AY1=ADD4(NBp[1],EBp[1]), AY2=ADD4(NBp[2],EBp[2]), AY3=ADD4(NBp[3],EBp[3]);
    float4 AY4=ADD4(NBp[4],EBp[4]), AY5=ADD4(NBp[5],EBp[5]), AY6=ADD4(NBp[6],EBp[6]), AY7=ADD4(NBp[7],EBp[7]);
    float4 AZ0=make_float4(0,0,0,0), AZ1=AZ0, AZ2=AZ0, AZ3=AZ0, AZ4=AZ0, AZ5=AZ0, AZ6=AZ0, AZ7=AZ0;

    DUAL_H(H0,0)  DUAL_H(H1,4)  DUAL_H(H2,8)   DUAL_H(H3,12)
    DUAL_H(H4,16) DUAL_H(H5,20) DUAL_H(H6,24)  DUAL_H(H7,28)
    DUAL_H(H8,32) DUAL_H(H9,36) DUAL_H(H10,40) DUAL_H(H11,44)
    DUAL_H(H12,48) DUAL_H(H13,52) DUAL_H(H14,56) DUAL_H(H15,60)

    if (on) {
        float4* yp = (float4*)(Yio + (size_t)n * 32);
        float4* zp = (float4*)(Z + (size_t)n * 32);
        yp[0]=AY0; yp[1]=AY1; yp[2]=AY2; yp[3]=AY3; yp[4]=AY4; yp[5]=AY5; yp[6]=AY6; yp[7]=AY7;
        zp[0]=AZ0; zp[1]=AZ1; zp[2]=AZ2; zp[3]=AZ3; zp[4]=AZ4; zp[5]=AZ5; zp[6]=AZ6; zp[7]=AZ7;
    }
}

// ---------------------------------------------------------------------------
// Kernel C: mlp+residual (layer 3) then decoder
// ---------------------------------------------------------------------------
__global__ __launch_bounds__(256, 1) void mlp_dec(
    const float* __restrict__ Y, const float* __restrict__ H,
    const float* __restrict__ mlpW, const float* __restrict__ mlp_b,
    const float* __restrict__ dW1, const float* __restrict__ db1,
    const float* __restrict__ dW2, const float* __restrict__ db2,
    float* __restrict__ out)
{
    int gid = blockIdx.x * 256 + threadIdx.x;
    bool on = gid < N_NODES;
    int n = on ? gid : N_NODES - 1;

    const float4* yv = (const float4*)(Y + (size_t)n * 32);
    float4 LY0,LY1,LY2,LY3,LY4,LY5,LY6,LY7;
    { float4 t;
      t=yv[0]; LEAKY4(LY0,t) t=yv[1]; LEAKY4(LY1,t)
      t=yv[2]; LEAKY4(LY2,t) t=yv[3]; LEAKY4(LY3,t)
      t=yv[4]; LEAKY4(LY4,t) t=yv[5]; LEAKY4(LY5,t)
      t=yv[6]; LEAKY4(LY6,t) t=yv[7]; LEAKY4(LY7,t) }

    const float4* MBp = (const float4*)mlp_b;
    float4 H0=MBp[0], H1=MBp[1], H2=MBp[2], H3=MBp[3], H4=MBp[4], H5=MBp[5], H6=MBp[6], H7=MBp[7];
    float4 H8=MBp[8], H9=MBp[9], H10=MBp[10], H11=MBp[11], H12=MBp[12], H13=MBp[13], H14=MBp[14], H15=MBp[15];

    MLP_LY(LY0,0)  MLP_LY(LY1,4)  MLP_LY(LY2,8)  MLP_LY(LY3,12)
    MLP_LY(LY4,16) MLP_LY(LY5,20) MLP_LY(LY6,24) MLP_LY(LY7,28)

    const float4* hp = (const float4*)(H + (size_t)n * 64);
    { float4 r;
      r=hp[0]; H0=ADD4(H0,r);   r=hp[1]; H1=ADD4(H1,r);
      r=hp[2]; H2=ADD4(H2,r);   r=hp[3]; H3=ADD4(H3,r);
      r=hp[4]; H4=ADD4(H4,r);   r=hp[5]; H5=ADD4(H5,r);
      r=hp[6]; H6=ADD4(H6,r);   r=hp[7]; H7=ADD4(H7,r);
      r=hp[8]; H8=ADD4(H8,r);   r=hp[9]; H9=ADD4(H9,r);
      r=hp[10]; H10=ADD4(H10,r); r=hp[11]; H11=ADD4(H11,r);
      r=hp[12]; H12=ADD4(H12,r); r=hp[13]; H13=ADD4(H13,r);
      r=hp[14]; H14=ADD4(H14,r); r=hp[15]; H15=ADD4(H15,r); }

    // decoder hidden: 24 outputs in D0..D5
    const float4* DB1 = (const float4*)db1;
    float4 D0=DB1[0], D1=DB1[1], D2=DB1[2], D3=DB1[3], D4=DB1[4], D5=DB1[5];

    DEC_H(H0,0)  DEC_H(H1,4)  DEC_H(H2,8)   DEC_H(H3,12)
    DEC_H(H4,16) DEC_H(H5,20) DEC_H(H6,24)  DEC_H(H7,28)
    DEC_H(H8,32) DEC_H(H9,36) DEC_H(H10,40) DEC_H(H11,44)
    DEC_H(H12,48) DEC_H(H13,52) DEC_H(H14,56) DEC_H(H15,60)

    float o0 = db2[0], o1 = db2[1], o2 = db2[2];
    OUT_D(D0,0) OUT_D(D1,4) OUT_D(D2,8) OUT_D(D3,12) OUT_D(D4,16) OUT_D(D5,20)

    if (on) {
        float* op = out + (size_t)n * 3;
        op[0] = o0; op[1] = o1; op[2] = o2;
    }
}

// ---------------------------------------------------------------------------
extern "C" void kernel_launch(void* const* d_in, const int* in_sizes, int n_in,
                              void* d_out, int out_size, void* d_ws, size_t ws_size,
                              hipStream_t stream)
{
    const float* x      = (const float*)d_in[0];
    const int*   esrc   = (const int*)d_in[2];
    const int*   edst   = (const int*)d_in[3];
    const float* ew     = (const float*)d_in[4];
    const float* enc_W1 = (const float*)d_in[5];
    const float* enc_b1 = (const float*)d_in[6];
    const float* enc_W2 = (const float*)d_in[7];
    const float* enc_b2 = (const float*)d_in[8];
    const float* dec_W1 = (const float*)d_in[9];
    const float* dec_b1 = (const float*)d_in[10];
    const float* dec_W2 = (const float*)d_in[11];
    const float* dec_b2 = (const float*)d_in[12];
    const float* ln_g   = (const float*)d_in[13];
    const float* ln_b   = (const float*)d_in[14];
    const float* node_W = (const float*)d_in[15];
    const float* node_b = (const float*)d_in[16];
    const float* edge_W = (const float*)d_in[17];
    const float* edge_b = (const float*)d_in[18];
    const float* mlp_W  = (const float*)d_in[19];
    const float* mlp_b  = (const float*)d_in[20];

    // Workspace: W1t[2048] | H[N*64] | Y[N*32] | Z[N*32] | ep[E int2] | ints
    float* W1t = (float*)d_ws;
    float* H  = W1t + 2048;
    float* Y  = H + (size_t)N_NODES * 64;
    float* Z  = Y + (size_t)N_NODES * 32;
    int2*  ep = (int2*)(Z + (size_t)N_NODES * 32);
    int* counts = (int*)(ep + N_EDGES);
    int* offs   = counts + N_NODES;
    int* cursor = offs + N_NODES + 1;
    int* bsum   = cursor + N_NODES;
    int* bscan  = bsum + NB1;

    const int nodeBlocks   = (N_NODES + 255) / 256;
    const int edgeBlocks   = (N_EDGES + 255) / 256;
    const int gatherBlocks = (N_NODES * 8 + 255) / 256;

    // --- CSR build + W1 transpose ---
    zero_counts<<<nodeBlocks, 256, 0, stream>>>(counts);
    count_kernel<<<edgeBlocks, 256, 0, stream>>>(edst, counts);
    scan1_kernel<<<NB1, 256, 0, stream>>>(counts, offs, bsum);
    scan2_kernel<<<1, 128, 0, stream>>>(bsum, bscan);
    scan3_kernel<<<NB1, 256, 0, stream>>>(offs, cursor, bscan);
    fill_kernel<<<edgeBlocks, 256, 0, stream>>>(esrc, edst, ew, cursor, ep);
    transpose_W1<<<8, 256, 0, stream>>>(enc_W1, W1t);

    // --- network ---
    enc_ln_gemm<<<nodeBlocks, 256, 0, stream>>>(
        x, W1t, enc_b1, enc_W2, enc_b2,
        ln_g, ln_b, node_W, node_b, edge_W, edge_b, H, Y, Z);

    for (int l = 0; l < LAYERS - 1; l++) {
        gather_kernel<<<gatherBlocks, 256, 0, stream>>>(offs, ep, Z, Y);
        mlp_ln_gemm<<<nodeBlocks, 256, 0, stream>>>(
            Y, H, Z,
            mlp_W + l * 32 * 64, mlp_b + l * 64,
            ln_g + (l + 1) * 64, ln_b + (l + 1) * 64,
            node_W + (l + 1) * 64 * 32, node_b + (l + 1) * 32,
            edge_W + (l + 1) * 64 * 32, edge_b + (l + 1) * 32);
    }
    gather_kernel<<<gatherBlocks, 256, 0, stream>>>(offs, ep, Z, Y);
    mlp_dec<<<nodeBlocks, 256, 0, stream>>>(
        Y, H, mlp_W + 3 * 32 * 64, mlp_b + 3 * 64,
        dec_W1, dec_b1, dec_W2, dec_b2, (float*)d_out);
}

// Round 9
// 596.307 us; speedup vs baseline: 7.9240x; 2.2395x over previous
//
#include <hip/hip_runtime.h>

#define N_NODES 100000
#define N_EDGES 1200000
#define LAYERS 4
#define SLOPE 0.01f

#define SCAN_ELEMS 1024                      // elems per scan1 block (256 thr x 4)
#define NB1 ((N_NODES + SCAN_ELEMS - 1) / SCAN_ELEMS)   // 98

__device__ __forceinline__ float leaky(float v) { return v >= 0.f ? v : SLOPE * v; }

// ---------------------------------------------------------------------------
// CSR build (counting sort by edge_dst) — runs once per launch
// ---------------------------------------------------------------------------
__global__ __launch_bounds__(256) void zero_counts(int* __restrict__ counts)
{
    int i = blockIdx.x * 256 + threadIdx.x;
    if (i < N_NODES) counts[i] = 0;
}

__global__ __launch_bounds__(256) void count_kernel(
    const int* __restrict__ dst, int* __restrict__ counts)
{
    int e = blockIdx.x * 256 + threadIdx.x;
    if (e < N_EDGES) atomicAdd(&counts[dst[e]], 1);
}

__global__ __launch_bounds__(256) void scan1_kernel(
    const int* __restrict__ counts, int* __restrict__ offs, int* __restrict__ bsum)
{
    __shared__ int s[256];
    int b = blockIdx.x, t = threadIdx.x;
    int base = b * SCAN_ELEMS;
    int v[4]; int sum = 0;
    #pragma unroll
    for (int u = 0; u < 4; u++) {
        int idx = base + t * 4 + u;
        int c = (idx < N_NODES) ? counts[idx] : 0;
        v[u] = sum; sum += c;
    }
    s[t] = sum; __syncthreads();
    for (int off = 1; off < 256; off <<= 1) {
        int y = (t >= off) ? s[t - off] : 0;
        __syncthreads();
        s[t] += y;
        __syncthreads();
    }
    int excl = s[t] - sum;
    #pragma unroll
    for (int u = 0; u < 4; u++) {
        int idx = base + t * 4 + u;
        if (idx < N_NODES) offs[idx] = excl + v[u];
    }
    if (t == 255) bsum[b] = s[255];
}

__global__ __launch_bounds__(128) void scan2_kernel(
    const int* __restrict__ bsum, int* __restrict__ bscan)
{
    __shared__ int s[128];
    int t = threadIdx.x;
    int c = (t < NB1) ? bsum[t] : 0;
    s[t] = c; __syncthreads();
    for (int off = 1; off < 128; off <<= 1) {
        int y = (t >= off) ? s[t - off] : 0;
        __syncthreads();
        s[t] += y;
        __syncthreads();
    }
    if (t < NB1) bscan[t] = s[t] - c;
}

__global__ __launch_bounds__(256) void scan3_kernel(
    int* __restrict__ offs, int* __restrict__ cursor, const int* __restrict__ bscan)
{
    int b = blockIdx.x, t = threadIdx.x;
    int base = b * SCAN_ELEMS;
    int add = bscan[b];
    #pragma unroll
    for (int u = 0; u < 4; u++) {
        int idx = base + t * 4 + u;
        if (idx < N_NODES) {
            int v = offs[idx] + add;
            offs[idx] = v;
            cursor[idx] = v;
        }
    }
    if (b == 0 && t == 0) offs[N_NODES] = N_EDGES;
}

// fill: one packed 8B (src, w) store per edge
__global__ __launch_bounds__(256) void fill_kernel(
    const int* __restrict__ src, const int* __restrict__ dst,
    const float* __restrict__ w, int* __restrict__ cursor,
    int2* __restrict__ ep)
{
    int e = blockIdx.x * 256 + threadIdx.x;
    if (e >= N_EDGES) return;
    int d = dst[e];
    int p = atomicAdd(&cursor[d], 1);
    ep[p] = make_int2(src[e], __float_as_int(w[e]));
}

// transpose W1 [16][128] -> W1t [128][16]  (runs once, trivial)
__global__ __launch_bounds__(256) void transpose_W1(
    const float* __restrict__ W1, float* __restrict__ W1t)
{
    int idx = blockIdx.x * 256 + threadIdx.x;
    if (idx < 16 * 128) {
        int r = idx / 128, c = idx % 128;
        W1t[c * 16 + r] = W1[idx];
    }
}

// ---------------------------------------------------------------------------
// Kernel A: encoder + LN(layer0) + dual GEMM(layer0).  4 lanes per node.
// Lane q owns features [q*16, q*16+16) of h/hn, Y/Z cols [q*8, q*8+8).
// W1t/b1 read from GLOBAL (8KB, L1-resident) — keeps LDS at ~49KB so
// 3 blocks/CU fit (was 58.9KB -> 2 blocks/CU -> 20% occupancy @ 145us).
// ---------------------------------------------------------------------------
__global__ __launch_bounds__(256) void enc_ln_gemm(
    const float* __restrict__ x,
    const float* __restrict__ W1t, const float* __restrict__ b1,
    const float* __restrict__ W2, const float* __restrict__ b2,
    const float* __restrict__ ln_g, const float* __restrict__ ln_b,
    const float* __restrict__ nodeW, const float* __restrict__ node_b,
    const float* __restrict__ edgeW, const float* __restrict__ edge_b,
    float* __restrict__ H, float* __restrict__ Y, float* __restrict__ Z)
{
    __shared__ float sW2[128 * 64];    // 32 KB
    __shared__ float sNW[64 * 32];     // 8 KB
    __shared__ float sEW[64 * 32];     // 8 KB
    __shared__ float sb2[64];
    __shared__ float sg[64], sb[64], sby[32];
    for (int idx = threadIdx.x; idx < 128 * 64; idx += 256) sW2[idx] = W2[idx];
    for (int idx = threadIdx.x; idx < 64 * 32; idx += 256) {
        sNW[idx] = nodeW[idx];
        sEW[idx] = edgeW[idx];
    }
    if (threadIdx.x < 64) {
        sb2[threadIdx.x] = b2[threadIdx.x];
        sg[threadIdx.x] = ln_g[threadIdx.x];
        sb[threadIdx.x] = ln_b[threadIdx.x];
    }
    if (threadIdx.x < 32) sby[threadIdx.x] = node_b[threadIdx.x] + edge_b[threadIdx.x];
    __syncthreads();

    int gid = blockIdx.x * 256 + threadIdx.x;
    int node = gid >> 2;
    int q = gid & 3;
    if (node >= N_NODES) return;

    float xi[16];
    const float4* xv = (const float4*)(x + (size_t)node * 16);
    #pragma unroll
    for (int i = 0; i < 4; i++) {
        float4 t = xv[i];
        xi[4 * i] = t.x; xi[4 * i + 1] = t.y; xi[4 * i + 2] = t.z; xi[4 * i + 3] = t.w;
    }

    // hidden: lane q computes t = tt*4 + q; W1t/b1 from global (L1-hot)
    float hid[32];
    #pragma unroll
    for (int tt = 0; tt < 32; tt++) {
        int t = tt * 4 + q;
        const float4* w = (const float4*)(W1t + t * 16);
        float a = b1[t];
        float4 w0 = w[0], w1 = w[1], w2 = w[2], w3 = w[3];
        a += xi[0] * w0.x + xi[1] * w0.y + xi[2] * w0.z + xi[3] * w0.w;
        a += xi[4] * w1.x + xi[5] * w1.y + xi[6] * w1.z + xi[7] * w1.w;
        a += xi[8] * w2.x + xi[9] * w2.y + xi[10] * w2.z + xi[11] * w2.w;
        a += xi[12] * w3.x + xi[13] * w3.y + xi[14] * w3.z + xi[15] * w3.w;
        hid[tt] = leaky(a);
    }

    // h chunk: j in [q*16, q*16+16); t = kk*4 + ss broadcast via shfl
    float h[16];
    #pragma unroll
    for (int jj = 0; jj < 16; jj++) h[jj] = sb2[q * 16 + jj];
    #pragma unroll
    for (int kk = 0; kk < 32; kk++) {
        #pragma unroll
        for (int ss = 0; ss < 4; ss++) {
            float v = __shfl(hid[kk], ss, 4);
            const float4* w = (const float4*)(sW2 + (kk * 4 + ss) * 64 + q * 16);
            float4 a = w[0], b = w[1], c = w[2], d = w[3];
            h[0]  += v * a.x; h[1]  += v * a.y; h[2]  += v * a.z; h[3]  += v * a.w;
            h[4]  += v * b.x; h[5]  += v * b.y; h[6]  += v * b.z; h[7]  += v * b.w;
            h[8]  += v * c.x; h[9]  += v * c.y; h[10] += v * c.z; h[11] += v * c.w;
            h[12] += v * d.x; h[13] += v * d.y; h[14] += v * d.z; h[15] += v * d.w;
        }
    }

    // LN over quad
    float s = 0.f, s2 = 0.f;
    #pragma unroll
    for (int jj = 0; jj < 16; jj++) { s += h[jj]; s2 += h[jj] * h[jj]; }
    s  += __shfl_xor(s, 1, 4);  s  += __shfl_xor(s, 2, 4);
    s2 += __shfl_xor(s2, 1, 4); s2 += __shfl_xor(s2, 2, 4);
    float mu  = s * (1.f / 64.f);
    float var = s2 * (1.f / 64.f) - mu * mu;
    float rs  = rsqrtf(var + 1e-5f);

    float hn[16];
    #pragma unroll
    for (int jj = 0; jj < 16; jj++)
        hn[jj] = (h[jj] - mu) * rs * sg[q * 16 + jj] + sb[q * 16 + jj];

    float4* hs = (float4*)(H + (size_t)node * 64 + q * 16);
    #pragma unroll
    for (int c = 0; c < 4; c++)
        hs[c] = make_float4(hn[4 * c], hn[4 * c + 1], hn[4 * c + 2], hn[4 * c + 3]);

    // dual GEMM: lane owns cols [q*8, q*8+8); k = ss*16 + kk
    float aY[8], aZ[8];
    #pragma unroll
    for (int jj = 0; jj < 8; jj++) { aY[jj] = sby[q * 8 + jj]; aZ[jj] = 0.f; }
    #pragma unroll
    for (int kk = 0; kk < 16; kk++) {
        #pragma unroll
        for (int ss = 0; ss < 4; ss++) {
            float v = __shfl(hn[kk], ss, 4);
            int k = ss * 16 + kk;
            const float4* nw = (const float4*)(sNW + k * 32 + q * 8);
            const float4* ew = (const float4*)(sEW + k * 32 + q * 8);
            float4 a = nw[0], b = nw[1], c = ew[0], d = ew[1];
            aY[0] += v * a.x; aY[1] += v * a.y; aY[2] += v * a.z; aY[3] += v * a.w;
            aY[4] += v * b.x; aY[5] += v * b.y; aY[6] += v * b.z; aY[7] += v * b.w;
            aZ[0] += v * c.x; aZ[1] += v * c.y; aZ[2] += v * c.z; aZ[3] += v * c.w;
            aZ[4] += v * d.x; aZ[5] += v * d.y; aZ[6] += v * d.z; aZ[7] += v * d.w;
        }
    }
    float4* yv = (float4*)(Y + (size_t)node * 32 + q * 8);
    float4* zv = (float4*)(Z + (size_t)node * 32 + q * 8);
    yv[0] = make_float4(aY[0], aY[1], aY[2], aY[3]);
    yv[1] = make_float4(aY[4], aY[5], aY[6], aY[7]);
    zv[0] = make_float4(aZ[0], aZ[1], aZ[2], aZ[3]);
    zv[1] = make_float4(aZ[4], aZ[5], aZ[6], aZ[7]);
}

// ---------------------------------------------------------------------------
// Gather: Y[n] += sum over incoming edges of w_e * Z[src_e]  (8 lanes/node)
// ---------------------------------------------------------------------------
__global__ __launch_bounds__(256) void gather_kernel(
    const int* __restrict__ offs, const int2* __restrict__ ep,
    const float* __restrict__ Z, float* __restrict__ Y)
{
    int gid = blockIdx.x * 256 + threadIdx.x;
    int node = gid >> 3;
    int lane = gid & 7;
    if (node >= N_NODES) return;
    int p0 = offs[node], p1 = offs[node + 1];
    float4 acc = make_float4(0.f, 0.f, 0.f, 0.f);
    for (int p = p0; p < p1; p++) {
        int2 pr = ep[p];
        float we = __int_as_float(pr.y);
        float4 zv = ((const float4*)Z)[(size_t)pr.x * 8 + lane];
        acc.x += we * zv.x; acc.y += we * zv.y;
        acc.z += we * zv.z; acc.w += we * zv.w;
    }
    float4* yp = (float4*)(Y + (size_t)node * 32) + lane;
    float4 y = *yp;
    y.x += acc.x; y.y += acc.y; y.z += acc.z; y.w += acc.w;
    *yp = y;
}

// ---------------------------------------------------------------------------
// Kernel B: mlp+residual (layer l) then LN + dual GEMM (layer l+1).
// 4 lanes/node; lane q owns features [q*16,q*16+16), Y/Z cols [q*8,q*8+8).
// ---------------------------------------------------------------------------
__global__ __launch_bounds__(256) void mlp_ln_gemm(
    float* __restrict__ Yio, float* __restrict__ H, float* __restrict__ Z,
    const float* __restrict__ mlpW, const float* __restrict__ mlp_b,
    const float* __restrict__ ln_g, const float* __restrict__ ln_b,
    const float* __restrict__ nodeW, const float* __restrict__ node_b,
    const float* __restrict__ edgeW, const float* __restrict__ edge_b)
{
    __shared__ float sMW[32 * 64];
    __shared__ float sNW[64 * 32];
    __shared__ float sEW[64 * 32];
    __shared__ float smb[64], sg[64], sb[64], sby[32];
    for (int idx = threadIdx.x; idx < 32 * 64; idx += 256) sMW[idx] = mlpW[idx];
    for (int idx = threadIdx.x; idx < 64 * 32; idx += 256) {
        sNW[idx] = nodeW[idx];
        sEW[idx] = edgeW[idx];
    }
    if (threadIdx.x < 64) {
        smb[threadIdx.x] = mlp_b[threadIdx.x];
        sg[threadIdx.x] = ln_g[threadIdx.x];
        sb[threadIdx.x] = ln_b[threadIdx.x];
    }
    if (threadIdx.x < 32) sby[threadIdx.x] = node_b[threadIdx.x] + edge_b[threadIdx.x];
    __syncthreads();

    int gid = blockIdx.x * 256 + threadIdx.x;
    int node = gid >> 2;
    int q = gid & 3;
    if (node >= N_NODES) return;

    // lane holds leaky(Y) for k in [q*8, q*8+8)
    float ly[8];
    const float4* yvin = (const float4*)(Yio + (size_t)node * 32 + q * 8);
    {
        float4 t0 = yvin[0], t1 = yvin[1];
        ly[0] = leaky(t0.x); ly[1] = leaky(t0.y); ly[2] = leaky(t0.z); ly[3] = leaky(t0.w);
        ly[4] = leaky(t1.x); ly[5] = leaky(t1.y); ly[6] = leaky(t1.z); ly[7] = leaky(t1.w);
    }
    // h chunk: j in [q*16, q*16+16); k = ss*8 + kk via shfl
    float h[16];
    #pragma unroll
    for (int jj = 0; jj < 16; jj++) h[jj] = smb[q * 16 + jj];
    #pragma unroll
    for (int kk = 0; kk < 8; kk++) {
        #pragma unroll
        for (int ss = 0; ss < 4; ss++) {
            float v = __shfl(ly[kk], ss, 4);
            const float4* w = (const float4*)(sMW + (ss * 8 + kk) * 64 + q * 16);
            float4 a = w[0], b = w[1], c = w[2], d = w[3];
            h[0]  += v * a.x; h[1]  += v * a.y; h[2]  += v * a.z; h[3]  += v * a.w;
            h[4]  += v * b.x; h[5]  += v * b.y; h[6]  += v * b.z; h[7]  += v * b.w;
            h[8]  += v * c.x; h[9]  += v * c.y; h[10] += v * c.z; h[11] += v * c.w;
            h[12] += v * d.x; h[13] += v * d.y; h[14] += v * d.z; h[15] += v * d.w;
        }
    }
    // residual
    float4* hp = (float4*)(H + (size_t)node * 64 + q * 16);
    #pragma unroll
    for (int c = 0; c < 4; c++) {
        float4 r = hp[c];
        h[4 * c] += r.x; h[4 * c + 1] += r.y; h[4 * c + 2] += r.z; h[4 * c + 3] += r.w;
    }
    // LN over quad
    float s = 0.f, s2 = 0.f;
    #pragma unroll
    for (int jj = 0; jj < 16; jj++) { s += h[jj]; s2 += h[jj] * h[jj]; }
    s  += __shfl_xor(s, 1, 4);  s  += __shfl_xor(s, 2, 4);
    s2 += __shfl_xor(s2, 1, 4); s2 += __shfl_xor(s2, 2, 4);
    float mu  = s * (1.f / 64.f);
    float var = s2 * (1.f / 64.f) - mu * mu;
    float rs  = rsqrtf(var + 1e-5f);

    float hn[16];
    #pragma unroll
    for (int jj = 0; jj < 16; jj++)
        hn[jj] = (h[jj] - mu) * rs * sg[q * 16 + jj] + sb[q * 16 + jj];
    #pragma unroll
    for (int c = 0; c < 4; c++)
        hp[c] = make_float4(hn[4 * c], hn[4 * c + 1], hn[4 * c + 2], hn[4 * c + 3]);

    // dual GEMM
    float aY[8], aZ[8];
    #pragma unroll
    for (int jj = 0; jj < 8; jj++) { aY[jj] = sby[q * 8 + jj]; aZ[jj] = 0.f; }
    #pragma unroll
    for (int kk = 0; kk < 16; kk++) {
        #pragma unroll
        for (int ss = 0; ss < 4; ss++) {
            float v = __shfl(hn[kk], ss, 4);
            int k = ss * 16 + kk;
            const float4* nw = (const float4*)(sNW + k * 32 + q * 8);
            const float4* ew = (const float4*)(sEW + k * 32 + q * 8);
            float4 a = nw[0], b = nw[1], c = ew[0], d = ew[1];
            aY[0] += v * a.x; aY[1] += v * a.y; aY[2] += v * a.z; aY[3] += v * a.w;
            aY[4] += v * b.x; aY[5] += v * b.y; aY[6] += v * b.z; aY[7] += v * b.w;
            aZ[0] += v * c.x; aZ[1] += v * c.y; aZ[2] += v * c.z; aZ[3] += v * c.w;
            aZ[4] += v * d.x; aZ[5] += v * d.y; aZ[6] += v * d.z; aZ[7] += v * d.w;
        }
    }
    float4* yo = (float4*)(Yio + (size_t)node * 32 + q * 8);
    float4* zv = (float4*)(Z + (size_t)node * 32 + q * 8);
    yo[0] = make_float4(aY[0], aY[1], aY[2], aY[3]);
    yo[1] = make_float4(aY[4], aY[5], aY[6], aY[7]);
    zv[0] = make_float4(aZ[0], aZ[1], aZ[2], aZ[3]);
    zv[1] = make_float4(aZ[4], aZ[5], aZ[6], aZ[7]);
}

// ---------------------------------------------------------------------------
// Kernel C: mlp+residual (layer 3) then decoder.  4 lanes/node.
// ---------------------------------------------------------------------------
__global__ __launch_bounds__(256) void mlp_dec(
    const float* __restrict__ Y, const float* __restrict__ H,
    const float* __restrict__ mlpW, const float* __restrict__ mlp_b,
    const float* __restrict__ dW1, const float* __restrict__ db1,
    const float* __restrict__ dW2, const float* __restrict__ db2,
    float* __restrict__ out)
{
    __shared__ float sMW[32 * 64];
    __shared__ float smb[64];
    __shared__ float sW1t[24 * 65];   // [t][k] = dW1[k][t], stride 65 (bank spread)
    __shared__ float sb1[24];
    __shared__ float sW2[24 * 3];
    __shared__ float sb2v[3];
    for (int idx = threadIdx.x; idx < 32 * 64; idx += 256) sMW[idx] = mlpW[idx];
    for (int idx = threadIdx.x; idx < 64 * 24; idx += 256) {
        int k = idx / 24, t = idx % 24;
        sW1t[t * 65 + k] = dW1[idx];
    }
    if (threadIdx.x < 64) smb[threadIdx.x] = mlp_b[threadIdx.x];
    if (threadIdx.x < 24) sb1[threadIdx.x] = db1[threadIdx.x];
    if (threadIdx.x < 72) sW2[threadIdx.x] = dW2[threadIdx.x];
    if (threadIdx.x < 3)  sb2v[threadIdx.x] = db2[threadIdx.x];
    __syncthreads();

    int gid = blockIdx.x * 256 + threadIdx.x;
    int node = gid >> 2;
    int q = gid & 3;
    if (node >= N_NODES) return;

    float ly[8];
    const float4* yvin = (const float4*)(Y + (size_t)node * 32 + q * 8);
    {
        float4 t0 = yvin[0], t1 = yvin[1];
        ly[0] = leaky(t0.x); ly[1] = leaky(t0.y); ly[2] = leaky(t0.z); ly[3] = leaky(t0.w);
        ly[4] = leaky(t1.x); ly[5] = leaky(t1.y); ly[6] = leaky(t1.z); ly[7] = leaky(t1.w);
    }
    float h[16];
    #pragma unroll
    for (int jj = 0; jj < 16; jj++) h[jj] = smb[q * 16 + jj];
    #pragma unroll
    for (int kk = 0; kk < 8; kk++) {
        #pragma unroll
        for (int ss = 0; ss < 4; ss++) {
            float v = __shfl(ly[kk], ss, 4);
            const float4* w = (const float4*)(sMW + (ss * 8 + kk) * 64 + q * 16);
            float4 a = w[0], b = w[1], c = w[2], d = w[3];
            h[0]  += v * a.x; h[1]  += v * a.y; h[2]  += v * a.z; h[3]  += v * a.w;
            h[4]  += v * b.x; h[5]  += v * b.y; h[6]  += v * b.z; h[7]  += v * b.w;
            h[8]  += v * c.x; h[9]  += v * c.y; h[10] += v * c.z; h[11] += v * c.w;
            h[12] += v * d.x; h[13] += v * d.y; h[14] += v * d.z; h[15] += v * d.w;
        }
    }
    const float4* hp = (const float4*)(H + (size_t)node * 64 + q * 16);
    #pragma unroll
    for (int c = 0; c < 4; c++) {
        float4 r = hp[c];
        h[4 * c] += r.x; h[4 * c + 1] += r.y; h[4 * c + 2] += r.z; h[4 * c + 3] += r.w;
    }
    // decoder hidden: lane q owns t in [q*6, q*6+6); k = ss*16+kk via shfl
    float hid[6];
    #pragma unroll
    for (int t = 0; t < 6; t++) hid[t] = sb1[q * 6 + t];
    #pragma unroll
    for (int kk = 0; kk < 16; kk++) {
        #pragma unroll
        for (int ss = 0; ss < 4; ss++) {
            float v = __shfl(h[kk], ss, 4);
            int k = ss * 16 + kk;
            #pragma unroll
            for (int t = 0; t < 6; t++)
                hid[t] += v * sW1t[(q * 6 + t) * 65 + k];
        }
    }
    float o0 = 0.f, o1 = 0.f, o2 = 0.f;
    #pragma unroll
    for (int t = 0; t < 6; t++) {
        float lt = leaky(hid[t]);
        int tg = q * 6 + t;
        o0 += lt * sW2[tg * 3 + 0];
        o1 += lt * sW2[tg * 3 + 1];
        o2 += lt * sW2[tg * 3 + 2];
    }
    o0 += __shfl_xor(o0, 1, 4); o0 += __shfl_xor(o0, 2, 4);
    o1 += __shfl_xor(o1, 1, 4); o1 += __shfl_xor(o1, 2, 4);
    o2 += __shfl_xor(o2, 1, 4); o2 += __shfl_xor(o2, 2, 4);
    if (q == 0) {
        float* op = out + (size_t)node * 3;
        op[0] = o0 + sb2v[0]; op[1] = o1 + sb2v[1]; op[2] = o2 + sb2v[2];
    }
}

// ---------------------------------------------------------------------------
extern "C" void kernel_launch(void* const* d_in, const int* in_sizes, int n_in,
                              void* d_out, int out_size, void* d_ws, size_t ws_size,
                              hipStream_t stream)
{
    const float* x      = (const float*)d_in[0];
    const int*   esrc   = (const int*)d_in[2];
    const int*   edst   = (const int*)d_in[3];
    const float* ew     = (const float*)d_in[4];
    const float* enc_W1 = (const float*)d_in[5];
    const float* enc_b1 = (const float*)d_in[6];
    const float* enc_W2 = (const float*)d_in[7];
    const float* enc_b2 = (const float*)d_in[8];
    const float* dec_W1 = (const float*)d_in[9];
    const float* dec_b1 = (const float*)d_in[10];
    const float* dec_W2 = (const float*)d_in[11];
    const float* dec_b2 = (const float*)d_in[12];
    const float* ln_g   = (const float*)d_in[13];
    const float* ln_b   = (const float*)d_in[14];
    const float* node_W = (const float*)d_in[15];
    const float* node_b = (const float*)d_in[16];
    const float* edge_W = (const float*)d_in[17];
    const float* edge_b = (const float*)d_in[18];
    const float* mlp_W  = (const float*)d_in[19];
    const float* mlp_b  = (const float*)d_in[20];

    // Workspace: W1t[2048] | H[N*64] | Y[N*32] | Z[N*32] | ep[E int2] | ints
    float* W1t = (float*)d_ws;
    float* H  = W1t + 2048;
    float* Y  = H + (size_t)N_NODES * 64;
    float* Z  = Y + (size_t)N_NODES * 32;
    int2*  ep = (int2*)(Z + (size_t)N_NODES * 32);
    int* counts = (int*)(ep + N_EDGES);
    int* offs   = counts + N_NODES;          // N_NODES+1 entries
    int* cursor = offs + N_NODES + 1;
    int* bsum   = cursor + N_NODES;
    int* bscan  = bsum + NB1;

    const int nodeBlocks   = (N_NODES + 255) / 256;
    const int node4Blocks  = (N_NODES * 4 + 255) / 256;
    const int edgeBlocks   = (N_EDGES + 255) / 256;
    const int gatherBlocks = (N_NODES * 8 + 255) / 256;

    // --- CSR build (counting sort by dst) + W1 transpose ---
    zero_counts<<<nodeBlocks, 256, 0, stream>>>(counts);
    count_kernel<<<edgeBlocks, 256, 0, stream>>>(edst, counts);
    scan1_kernel<<<NB1, 256, 0, stream>>>(counts, offs, bsum);
    scan2_kernel<<<1, 128, 0, stream>>>(bsum, bscan);
    scan3_kernel<<<NB1, 256, 0, stream>>>(offs, cursor, bscan);
    fill_kernel<<<edgeBlocks, 256, 0, stream>>>(esrc, edst, ew, cursor, ep);
    transpose_W1<<<8, 256, 0, stream>>>(enc_W1, W1t);

    // --- network ---
    enc_ln_gemm<<<node4Blocks, 256, 0, stream>>>(
        x, W1t, enc_b1, enc_W2, enc_b2,
        ln_g, ln_b, node_W, node_b, edge_W, edge_b, H, Y, Z);

    for (int l = 0; l < LAYERS - 1; l++) {
        gather_kernel<<<gatherBlocks, 256, 0, stream>>>(offs, ep, Z, Y);
        mlp_ln_gemm<<<node4Blocks, 256, 0, stream>>>(
            Y, H, Z,
            mlp_W + l * 32 * 64, mlp_b + l * 64,
            ln_g + (l + 1) * 64, ln_b + (l + 1) * 64,
            node_W + (l + 1) * 64 * 32, node_b + (l + 1) * 32,
            edge_W + (l + 1) * 64 * 32, edge_b + (l + 1) * 32);
    }
    gather_kernel<<<gatherBlocks, 256, 0, stream>>>(offs, ep, Z, Y);
    mlp_dec<<<node4Blocks, 256, 0, stream>>>(
        Y, H, mlp_W + 3 * 32 * 64, mlp_b + 3 * 64,
        dec_W1, dec_b1, dec_W2, dec_b2, (float*)d_out);
}